// Round 4
// baseline (341.213 us; speedup 1.0000x reference)
//
#include <hip/hip_runtime.h>
#include <stdint.h>

#define SS 64
#define NN 4096
#define FF 32
#define HH 64
#define OO 2
#define G3 192

typedef float f32x4 __attribute__((ext_vector_type(4)));
typedef short bf16x8 __attribute__((ext_vector_type(8)));
typedef unsigned short u16x8 __attribute__((ext_vector_type(8)));

__device__ __forceinline__ unsigned short f2bf(float f) {
  union { float f; uint32_t u; } v; v.f = f;
  uint32_t u = v.u;
  uint32_t r = (u + 0x7FFFu + ((u >> 16) & 1u)) >> 16;
  return (unsigned short)r;
}
__device__ __forceinline__ float bf2f(unsigned short s) {
  union { uint32_t u; float f; } v; v.u = ((uint32_t)s) << 16;
  return v.f;
}

// ---------------- fused: adj f32->bf16 (blocks 0..4095) + support (blocks 4096..8191) ----------------
__global__ __launch_bounds__(256) void k_prep(const float* __restrict__ adj,
                                              unsigned short* __restrict__ adjb,
                                              const float* __restrict__ x,
                                              const float* __restrict__ W1,
                                              const float* __restrict__ b1,
                                              unsigned short* __restrict__ Bt) {
  int tid = threadIdx.x;
  if (blockIdx.x < 4096) {
    int id = blockIdx.x * 256 + tid;
    #pragma unroll
    for (int it = 0; it < 4; ++it) {
      int i = id + it * 1048576;
      float4 v = ((const float4*)adj)[i];
      ushort4 r;
      r.x = f2bf(v.x); r.y = f2bf(v.y); r.z = f2bf(v.z); r.w = f2bf(v.w);
      ((ushort4*)adjb)[i] = r;
    }
    return;
  }
  __shared__ float xl[64][33];
  __shared__ float w1l[32 * 64];
  __shared__ float b1l[64];
  int bs = blockIdx.x - 4096;
  int s = bs >> 6, jb = (bs & 63) << 6;
  const float4* xg = (const float4*)(x + ((size_t)s * NN + jb) * FF);
  #pragma unroll
  for (int i = 0; i < 2; ++i) {
    int idx = tid + i * 256;
    float4 v = xg[idx];
    int j = idx >> 3, f = (idx & 7) << 2;
    xl[j][f] = v.x; xl[j][f + 1] = v.y; xl[j][f + 2] = v.z; xl[j][f + 3] = v.w;
  }
  #pragma unroll
  for (int i = 0; i < 2; ++i) {
    int idx = tid + i * 256;
    float4 v = ((const float4*)W1)[idx];
    w1l[idx * 4] = v.x; w1l[idx * 4 + 1] = v.y; w1l[idx * 4 + 2] = v.z; w1l[idx * 4 + 3] = v.w;
  }
  if (tid < 64) b1l[tid] = b1[tid];
  __syncthreads();
  int jj = tid & 63, hq = tid >> 6;
  unsigned short* outb = Bt + (size_t)(s * HH) * NN + jb + jj;
  #pragma unroll
  for (int hh = 0; hh < 16; ++hh) {
    int h = hq * 16 + hh;
    float acc = b1l[h];
    #pragma unroll
    for (int f = 0; f < FF; ++f) acc += xl[jj][f] * w1l[f * 64 + h];
    outb[(size_t)h * NN] = f2bf(acc);
  }
}

// =====================================================================
// GEMM1: 256x256 tile, BK=64, 8 waves. 3-barrier full-prefetch K-tile:
//   B_t -> 24 ds_read (all frags) -> lgkm0+midbar -> stage t+2 (8 loads)
//   -> 64 MFMA (no LDS deps) -> vmcnt(8) -> E_t.  Never drains in-loop.
// Epilogue fuses support2: B2t[s*2+o][i] = b2[o] + sum_h relu(C)*W2
// =====================================================================
#define SBAR()   asm volatile("s_barrier" ::: "memory")
#define LGKM0()  asm volatile("s_waitcnt lgkmcnt(0)" ::: "memory")
#define VMCNT8() asm volatile("s_waitcnt vmcnt(8)" ::: "memory")
#define VMCNT0() asm volatile("s_waitcnt vmcnt(0)" ::: "memory")

__global__ __launch_bounds__(512, 2) void k_gemm1_fp(
    const unsigned short* __restrict__ A,
    const unsigned short* __restrict__ B,
    const float* __restrict__ W2,
    const float* __restrict__ b2,
    unsigned short* __restrict__ B2t) {
  __shared__ __align__(16) char lds[131072];
  const int tid = threadIdx.x;
  const int wid = tid >> 6, l = tid & 63;
  const int wr2 = wid >> 2, wc2 = wid & 3;

  int bid = blockIdx.x;
  int swz = (bid & 7) * 32 + (bid >> 3);   // bijective XCD swizzle (256 = 8*32)
  const int i0 = (swz >> 4) * 256;
  const int c0 = (swz & 15) * 256;

  // fragment-read lane constants (logical col XOR (row&7)<<4 swizzle)
  const int aRow = (wr2 * 64 + (l & 15)) * 128;
  const int bRow = (wc2 * 32 + (l & 15)) * 128;
  const int colKK0 = (((l >> 4) * 16)) ^ ((l & 7) << 4);
  const int colKK1 = ((64 + (l >> 4) * 16)) ^ ((l & 7) << 4);

  // staging lane constants: linear LDS dest, inverse-swizzled global source
  const int srow = tid >> 3;                         // 0..63
  const int scol = (((tid & 7) ^ (srow & 7)) << 4);  // source col chunk ^ row&7
  const char* gA = (const char*)A + (size_t)(i0 + srow) * 8192 + scol;
  const char* gB = (const char*)B + (size_t)(c0 + srow) * 8192 + scol;
  char* ldsW = (char*)lds + wid * 1024;
  const char* ldsR = (const char*)lds;

  f32x4 acc[2][2][4][2];
  #pragma unroll
  for (int qm = 0; qm < 2; ++qm)
    #pragma unroll
    for (int qn = 0; qn < 2; ++qn)
      #pragma unroll
      for (int m = 0; m < 4; ++m)
        #pragma unroll
        for (int n = 0; n < 2; ++n) acc[qm][qn][m][n] = {0.f, 0.f, 0.f, 0.f};

  bf16x8 af[2][4][2];    // [qm][m][kk]
  bf16x8 bfr[2][2][2];   // [qn][n][kk]

#define STAGE_HALF(GP, OPOFF, KT, QH, BUF) do {                                      \
    const char* _g0 = (GP) + (size_t)((QH) * 128) * 8192 + (size_t)(((KT) & 63)) * 128; \
    char* _l0 = ldsW + (BUF) * 65536 + (OPOFF) + (QH) * 16384;                       \
    __builtin_amdgcn_global_load_lds(                                                \
        (const __attribute__((address_space(1))) void*)_g0,                          \
        (__attribute__((address_space(3))) void*)_l0, 16, 0, 0);                     \
    __builtin_amdgcn_global_load_lds(                                                \
        (const __attribute__((address_space(1))) void*)(_g0 + (size_t)64 * 8192),    \
        (__attribute__((address_space(3))) void*)(_l0 + 8192), 16, 0, 0);            \
  } while (0)

#define STAGE_A(KT, QH, BUF) STAGE_HALF(gA, 0, KT, QH, BUF)
#define STAGE_B(KT, QH, BUF) STAGE_HALF(gB, 32768, KT, QH, BUF)
#define STAGE_TILE(KT, BUF) do {                                                     \
    STAGE_A(KT, 0, BUF); STAGE_A(KT, 1, BUF);                                        \
    STAGE_B(KT, 0, BUF); STAGE_B(KT, 1, BUF); } while (0)

#define READ_TILE(BUF) do {                                                          \
    _Pragma("unroll")                                                                \
    for (int _qm = 0; _qm < 2; ++_qm)                                                \
      _Pragma("unroll")                                                              \
      for (int _m = 0; _m < 4; ++_m) {                                               \
        const char* _p = ldsR + (BUF) * 65536 + _qm * 16384 + aRow + _m * 2048;      \
        af[_qm][_m][0] = *(const bf16x8*)(_p + colKK0);                              \
        af[_qm][_m][1] = *(const bf16x8*)(_p + colKK1);                              \
      }                                                                              \
    _Pragma("unroll")                                                                \
    for (int _qn = 0; _qn < 2; ++_qn)                                                \
      _Pragma("unroll")                                                              \
      for (int _n = 0; _n < 2; ++_n) {                                               \
        const char* _p = ldsR + (BUF) * 65536 + 32768 + _qn * 16384 + bRow + _n * 2048; \
        bfr[_qn][_n][0] = *(const bf16x8*)(_p + colKK0);                             \
        bfr[_qn][_n][1] = *(const bf16x8*)(_p + colKK1);                             \
      } } while (0)

#define MFMA_ALL() do {                                                              \
    __builtin_amdgcn_s_setprio(1);                                                   \
    _Pragma("unroll")                                                                \
    for (int _qm = 0; _qm < 2; ++_qm)                                                \
      _Pragma("unroll")                                                              \
      for (int _qn = 0; _qn < 2; ++_qn)                                              \
        _Pragma("unroll")                                                            \
        for (int _kk = 0; _kk < 2; ++_kk)                                            \
          _Pragma("unroll")                                                          \
          for (int _m = 0; _m < 4; ++_m)                                             \
            _Pragma("unroll")                                                        \
            for (int _n = 0; _n < 2; ++_n)                                           \
              acc[_qm][_qn][_m][_n] = __builtin_amdgcn_mfma_f32_16x16x32_bf16(       \
                  af[_qm][_m][_kk], bfr[_qn][_n][_kk], acc[_qm][_qn][_m][_n], 0, 0, 0); \
    __builtin_amdgcn_s_setprio(0);                                                   \
  } while (0)

#define KTILE(CUR, KT) do {                                                          \
    READ_TILE(CUR);                                                                  \
    LGKM0();                                                                         \
    SBAR();                   /* all waves consumed buf[CUR] -> safe to overwrite */ \
    STAGE_TILE((KT) + 2, CUR);                                                       \
    MFMA_ALL();                                                                      \
    VMCNT8();                 /* tile KT+1 (issued last K-tile) complete */          \
    SBAR();                                                                          \
  } while (0)

  // Prologue: tile0 -> buf0, tile1 -> buf1 (16 loads); vmcnt(8) completes tile0.
  STAGE_TILE(0, 0);
  STAGE_TILE(1, 1);
  VMCNT8();
  SBAR();

  for (int it = 0; it < 32; ++it) {
    KTILE(0, it * 2);
    KTILE(1, it * 2 + 1);
  }

  VMCNT0();
  __syncthreads();   // drain; LDS reusable for reduction

  // ---- fused support2 epilogue ----
  float* part = (float*)lds;                 // [8][2048] f32 = 64 KiB
  const int wc1 = wc2 & 1;
  const int l15 = l & 15;
  float w2r[2][2];
  #pragma unroll
  for (int n = 0; n < 2; ++n)
    #pragma unroll
    for (int o = 0; o < 2; ++o)
      w2r[n][o] = W2[(wc1 * 32 + n * 16 + l15) * 2 + o];

  const int pidx = wc1 * 4 + (l15 >> 2);
  const int gbase = (l >> 4) * 4;
  #pragma unroll
  for (int qm = 0; qm < 2; ++qm)
    #pragma unroll
    for (int m = 0; m < 4; ++m)
      #pragma unroll
      for (int r = 0; r < 4; ++r) {
        const int lr = qm * 128 + wr2 * 64 + m * 16 + gbase + r;
        #pragma unroll
        for (int qn = 0; qn < 2; ++qn) {
          float a0 = acc[qm][qn][m][0][r]; a0 = a0 > 0.f ? a0 : 0.f;
          float a1 = acc[qm][qn][m][1][r]; a1 = a1 > 0.f ? a1 : 0.f;
          const int sg = qn * 2 + (wc2 >> 1);
          #pragma unroll
          for (int o = 0; o < 2; ++o) {
            float v = a0 * w2r[0][o] + a1 * w2r[1][o];
            v += __shfl_xor(v, 1);
            v += __shfl_xor(v, 2);
            if ((l & 3) == 0)
              part[pidx * 2048 + (sg * 2 + o) * 256 + lr] = v;
          }
        }
      }
  __syncthreads();
  {
    const int so = tid >> 6;          // sg*2+o
    const int o = so & 1, sg = so >> 1;
    const int ib = (tid & 63) * 4;
    const float bo = b2[o];
    unsigned short tmp[4];
    #pragma unroll
    for (int k = 0; k < 4; ++k) {
      const int v = so * 256 + ib + k;
      float s_ = 0.f;
      #pragma unroll
      for (int p = 0; p < 8; ++p) s_ += part[p * 2048 + v];
      tmp[k] = f2bf(s_ + bo);
    }
    ushort4 outv; outv.x = tmp[0]; outv.y = tmp[1]; outv.z = tmp[2]; outv.w = tmp[3];
    *(ushort4*)(B2t + (size_t)(((c0 >> 6) + sg) * 2 + o) * 4096 + i0 + ib) = outv;
  }
}

// ---------------- shared MFMA GEMM core (m97-style, used by gemm2) ----------------
__device__ __forceinline__ void gemm_core(const unsigned short* __restrict__ A,
                                          const unsigned short* __restrict__ B,
                                          int i0, int c0, int k0base, int ksteps,
                                          f32x4 acc[4][4],
                                          unsigned short* Als, unsigned short* Bls) {
  const int tid = threadIdx.x;
  const int w = tid >> 6, l = tid & 63;
  const int srow = (l >> 2);
  const int scol = (l & 3) * 16;   // bytes within 64B row
  for (int kt = 0; kt < ksteps; ++kt) {
    int k0 = k0base + kt * 32;
    #pragma unroll
    for (int q = 0; q < 2; ++q) {
      int r = w * 32 + q * 16 + srow;
      const char* ga = (const char*)(A + (size_t)(i0 + r) * 4096 + k0) + scol;
      __builtin_amdgcn_global_load_lds(
          (const __attribute__((address_space(1))) void*)ga,
          (__attribute__((address_space(3))) void*)((char*)Als + w * 2048 + q * 1024),
          16, 0, 0);
      const char* gb = (const char*)(B + (size_t)(c0 + r) * 4096 + k0) + scol;
      __builtin_amdgcn_global_load_lds(
          (const __attribute__((address_space(1))) void*)gb,
          (__attribute__((address_space(3))) void*)((char*)Bls + w * 2048 + q * 1024),
          16, 0, 0);
    }
    __syncthreads();
    const int wr = w >> 1, wc = w & 1;
    bf16x8 af[4], bff[4];
    #pragma unroll
    for (int m = 0; m < 4; ++m)
      af[m] = *(const bf16x8*)(Als + (wr * 64 + m * 16 + (l & 15)) * 32 + (l >> 4) * 8);
    #pragma unroll
    for (int n = 0; n < 4; ++n)
      bff[n] = *(const bf16x8*)(Bls + (wc * 64 + n * 16 + (l & 15)) * 32 + (l >> 4) * 8);
    #pragma unroll
    for (int m = 0; m < 4; ++m)
      #pragma unroll
      for (int n = 0; n < 4; ++n)
        acc[m][n] = __builtin_amdgcn_mfma_f32_16x16x32_bf16(af[m], bff[n], acc[m][n], 0, 0, 0);
    __syncthreads();
  }
}

// ---------------- GEMM2 split-K: Gp[ks][i][c2] partial f32 ----------------
__global__ __launch_bounds__(256) void k_gemm2(const unsigned short* __restrict__ A,
                                               const unsigned short* __restrict__ B,
                                               float* __restrict__ Gp) {
  __shared__ unsigned short Als[128 * 32], Bls[128 * 32];
  int id = blockIdx.x;
  int bi = id & 31, ks = id >> 5;
  int i0 = bi * 128;
  f32x4 acc[4][4];
  #pragma unroll
  for (int m = 0; m < 4; ++m)
    #pragma unroll
    for (int n = 0; n < 4; ++n) acc[m][n] = {0.f, 0.f, 0.f, 0.f};
  gemm_core(A, B, i0, 0, ks * 512, 16, acc, Als, Bls);
  float* outp = Gp + (size_t)ks * 4096 * 128;
  int l = threadIdx.x & 63, w = threadIdx.x >> 6;
  int wr = w >> 1, wc = w & 1;
  int rbase = i0 + wr * 64 + (l >> 4) * 4;
  int cbase = wc * 64 + (l & 15);
  #pragma unroll
  for (int m = 0; m < 4; ++m)
    #pragma unroll
    for (int n = 0; n < 4; ++n)
      #pragma unroll
      for (int r = 0; r < 4; ++r)
        outp[(size_t)(rbase + m * 16 + r) * 128 + cbase + n * 16] = acc[m][n][r];
}

// ---------------- reduce split-K + log_softmax -> R[s][i*2+o] f32 ----------------
__global__ __launch_bounds__(256) void k_lsm(const float* __restrict__ Gp,
                                             float* __restrict__ Rm) {
  __shared__ float Gacc[32][130];
  int i0 = blockIdx.x * 32;
  int tid = threadIdx.x;
  float4 v[4];
  #pragma unroll
  for (int i = 0; i < 4; ++i) v[i] = {0.f, 0.f, 0.f, 0.f};
  for (int ks = 0; ks < 8; ++ks) {
    const float4* gp4 = ((const float4*)Gp) + (size_t)ks * 131072 + (size_t)i0 * 32;
    #pragma unroll
    for (int i = 0; i < 4; ++i) {
      float4 t = gp4[tid + i * 256];
      v[i].x += t.x; v[i].y += t.y; v[i].z += t.z; v[i].w += t.w;
    }
  }
  #pragma unroll
  for (int i = 0; i < 4; ++i) {
    int f4i = tid + i * 256, row = f4i >> 5, c = (f4i & 31) * 4;
    Gacc[row][c] = v[i].x; Gacc[row][c + 1] = v[i].y;
    Gacc[row][c + 2] = v[i].z; Gacc[row][c + 3] = v[i].w;
  }
  __syncthreads();
  #pragma unroll
  for (int j = 0; j < 8; ++j) {
    int p = j * 256 + tid;
    int ii = p & 31, s = p >> 5;
    float g0 = Gacc[ii][s * 2], g1 = Gacc[ii][s * 2 + 1];
    float m = fmaxf(g0, g1);
    float lse = m + logf(expf(g0 - m) + expf(g1 - m));
    float2 o_; o_.x = g0 - lse; o_.y = g1 - lse;
    *((float2*)(Rm + (size_t)s * 8192 + (size_t)(i0 + ii) * 2)) = o_;
  }
}

// ---------------- gi0 partial: part[ks][t][g] = R[t] . Wih0[g] over c-range ----------------
__global__ __launch_bounds__(256) void k_gi0(const float* __restrict__ Rm,
                                             const float* __restrict__ Wih0,
                                             float* __restrict__ part) {
  __shared__ float4 Wl[4 * 128];
  int gb = blockIdx.x % 48, ks = blockIdx.x / 48;
  int c0 = ks * 512;
  int tid = threadIdx.x;
  #pragma unroll
  for (int i = 0; i < 2; ++i) {
    int idx = tid + i * 256;
    int g = idx >> 7, c4 = idx & 127;
    Wl[g * 128 + c4] = ((const float4*)(Wih0 + (size_t)(gb * 4 + g) * 8192 + c0))[c4];
  }
  __syncthreads();
  int w = tid >> 6, lane = tid & 63;
  for (int pass = 0; pass < 16; ++pass) {
    int t = pass * 4 + w;
    float a0 = 0.f, a1 = 0.f, a2 = 0.f, a3 = 0.f;
    const float4* rg = (const float4*)(Rm + (size_t)t * 8192 + c0);
    #pragma unroll
    for (int i = 0; i < 2; ++i) {
      int c4 = i * 64 + lane;
      float4 r4 = rg[c4];
      float4 w0 = Wl[c4], w1 = Wl[128 + c4], w2 = Wl[256 + c4], w3 = Wl[384 + c4];
      a0 += r4.x * w0.x + r4.y * w0.y + r4.z * w0.z + r4.w * w0.w;
      a1 += r4.x * w1.x + r4.y * w1.y + r4.z * w1.z + r4.w * w1.w;
      a2 += r4.x * w2.x + r4.y * w2.y + r4.z * w2.z + r4.w * w2.w;
      a3 += r4.x * w3.x + r4.y * w3.y + r4.z * w3.z + r4.w * w3.w;
    }
    #pragma unroll
    for (int off = 1; off < 64; off <<= 1) {
      a0 += __shfl_xor(a0, off);
      a1 += __shfl_xor(a1, off);
      a2 += __shfl_xor(a2, off);
      a3 += __shfl_xor(a3, off);
    }
    if (lane == 0) {
      float4 o_; o_.x = a0; o_.y = a1; o_.z = a2; o_.w = a3;
      *((float4*)(part + ((size_t)ks * 64 + t) * 192 + gb * 4)) = o_;
    }
  }
}

__global__ __launch_bounds__(256) void k_gi0red(const float* __restrict__ part,
                                                const float* __restrict__ bih0,
                                                float* __restrict__ gi0) {
  int idx = blockIdx.x * 256 + threadIdx.x;
  if (idx < 12288) {
    float s_ = bih0[idx % 192];
    for (int ks = 0; ks < 16; ++ks) s_ += part[ks * 12288 + idx];
    gi0[idx] = s_;
  }
}

// ---------------- fused 2-layer GRU, batch 1, weights in VGPRs ----------------
// Layer-1 pipelined one step behind layer-0: 2 barriers/step, gi0 in LDS.
__global__ __launch_bounds__(192) void k_gru(const float* __restrict__ gi0,
                                             const float* __restrict__ Whh0,
                                             const float* __restrict__ bhh0,
                                             const float* __restrict__ Wih1,
                                             const float* __restrict__ Whh1,
                                             const float* __restrict__ bih1,
                                             const float* __restrict__ bhh1,
                                             float* __restrict__ out) {
  __shared__ float gil[64][192];   // 48KB: all precomputed input gates
  __shared__ float h0s[64], h1s[64], ys0s[64], gA[192], uA[192], vA[192];
  int g = threadIdx.x;
  float w0[64], wi1[64], wh1[64];
  #pragma unroll
  for (int k = 0; k < 16; ++k) {
    float4 t0 = ((const float4*)(Whh0 + (size_t)g * 64))[k];
    float4 t1 = ((const float4*)(Wih1 + (size_t)g * 64))[k];
    float4 t2 = ((const float4*)(Whh1 + (size_t)g * 64))[k];
    w0[k * 4] = t0.x; w0[k * 4 + 1] = t0.y; w0[k * 4 + 2] = t0.z; w0[k * 4 + 3] = t0.w;
    wi1[k * 4] = t1.x; wi1[k * 4 + 1] = t1.y; wi1[k * 4 + 2] = t1.z; wi1[k * 4 + 3] = t1.w;
    wh1[k * 4] = t2.x; wh1[k * 4 + 1] = t2.y; wh1[k * 4 + 2] = t2.z; wh1[k * 4 + 3] = t2.w;
  }
  float bh0 = bhh0[g], bi1 = bih1[g], bh1 = bhh1[g];
  // preload gi0 -> LDS (3072 float4s, 16 per thread)
  {
    float4* gf = (float4*)&gil[0][0];
    const float4* gs = (const float4*)gi0;
    #pragma unroll
    for (int i = 0; i < 16; ++i) gf[i * 192 + g] = gs[i * 192 + g];
  }
  if (g < 64) { h0s[g] = 0.f; h1s[g] = 0.f; ys0s[g] = 0.f; }
  __syncthreads();

  for (int t = 0; t <= 64; ++t) {
    const int tt = t & 63;
    // region 1: three dots (gh0 uses h0[t]; u,v use ys0[t-1], h1[t-1])
    float a0 = 0.f, a1 = 0.f, a2 = 0.f, a3 = 0.f;
    float b0 = 0.f, b1_ = 0.f, b2_ = 0.f, b3 = 0.f;
    float c0 = 0.f, c1 = 0.f, c2 = 0.f, c3 = 0.f;
    #pragma unroll
    for (int k = 0; k < 16; ++k) {
      float4 h4 = *(const float4*)&h0s[k * 4];
      float4 y4 = *(const float4*)&ys0s[k * 4];
      float4 g4 = *(const float4*)&h1s[k * 4];
      a0 += w0[k * 4] * h4.x;  a1 += w0[k * 4 + 1] * h4.y;
      a2 += w0[k * 4 + 2] * h4.z;  a3 += w0[k * 4 + 3] * h4.w;
      b0 += wi1[k * 4] * y4.x; b1_ += wi1[k * 4 + 1] * y4.y;
      b2_ += wi1[k * 4 + 2] * y4.z; b3 += wi1[k * 4 + 3] * y4.w;
      c0 += wh1[k * 4] * g4.x; c1 += wh1[k * 4 + 1] * g4.y;
      c2 += wh1[k * 4 + 2] * g4.z; c3 += wh1[k * 4 + 3] * g4.w;
    }
    float gh = (a0 + a1) + (a2 + a3) + bh0;
    gA[g] = (g < 128) ? (gil[tt][g] + gh) : gh;
    uA[g] = (b0 + b1_) + (b2_ + b3) + bi1;
    vA[g] = (c0 + c1) + (c2 + c3) + bh1;
    __syncthreads();
    // region 2: parallel updates (layer0 by g<64, layer1 by 64<=g<128)
    if (g < 64) {
      if (t < 64) {
        float r = 1.f / (1.f + expf(-gA[g]));
        float z = 1.f / (1.f + expf(-gA[g + 64]));
        float n = tanhf(gil[tt][128 + g] + r * gA[g + 128]);
        float hnew = (1.f - z) * n + z * h0s[g];
        h0s[g] = hnew; ys0s[g] = hnew;
      }
    } else if (g < 128 && t > 0) {
      int gg = g - 64;
      float r = 1.f / (1.f + expf(-(uA[gg] + vA[gg])));
      float z = 1.f / (1.f + expf(-(uA[gg + 64] + vA[gg + 64])));
      float n = tanhf(uA[gg + 128] + r * vA[gg + 128]);
      float h1new = (1.f - z) * n + z * h1s[gg];
      h1s[gg] = h1new;
      out[(t - 1) * 64 + gg] = h1new;
    }
    __syncthreads();
  }
  if (g < 64) { out[4096 + g] = h0s[g]; out[4096 + 64 + g] = h1s[g]; }
}

extern "C" void kernel_launch(void* const* d_in, const int* in_sizes, int n_in,
                              void* d_out, int out_size, void* d_ws, size_t ws_size,
                              hipStream_t stream) {
  const float* x    = (const float*)d_in[0];
  const float* adj  = (const float*)d_in[1];
  const float* W1   = (const float*)d_in[2];
  const float* b1   = (const float*)d_in[3];
  const float* W2   = (const float*)d_in[4];
  const float* b2   = (const float*)d_in[5];
  const float* Wih0 = (const float*)d_in[6];
  const float* Whh0 = (const float*)d_in[7];
  const float* bih0 = (const float*)d_in[8];
  const float* bhh0 = (const float*)d_in[9];
  const float* Wih1 = (const float*)d_in[10];
  const float* Whh1 = (const float*)d_in[11];
  const float* bih1 = (const float*)d_in[12];
  const float* bhh1 = (const float*)d_in[13];
  float* out = (float*)d_out;

  char* ws = (char*)d_ws;
  unsigned short* adjb = (unsigned short*)ws;
  unsigned short* Bt   = (unsigned short*)(ws + 33554432);
  float* Gp   = (float*)(ws + 33554432);              // 16MB (Bt dead after gemm1)
  float* Rm   = (float*)(ws + 50331648);              // 2MB
  float* part = (float*)(ws + 52428800);              // 768KB
  float* gi0  = (float*)(ws + 53215232);              // 48KB
  unsigned short* B2t = (unsigned short*)(ws + 53264384); // 1MB

  k_prep<<<8192, 256, 0, stream>>>(adj, adjb, x, W1, b1, Bt);
  k_gemm1_fp<<<256, 512, 0, stream>>>(adjb, Bt, W2, b2, B2t);
  k_gemm2<<<256, 256, 0, stream>>>(adjb, B2t, Gp);
  k_lsm<<<128, 256, 0, stream>>>(Gp, Rm);
  k_gi0<<<768, 256, 0, stream>>>(Rm, Wih0, part);
  k_gi0red<<<48, 256, 0, stream>>>(part, bih0, gi0);
  k_gru<<<1, 192, 0, stream>>>(gi0, Whh0, bhh0, Wih1, Whh1, bih1, bhh1, out);
}

// Round 5
// 263.609 us; speedup vs baseline: 1.2944x; 1.2944x over previous
//
#include <hip/hip_runtime.h>
#include <stdint.h>

#define SS 64
#define NN 4096
#define FF 32
#define HH 64
#define OO 2
#define G3 192

typedef float f32x4 __attribute__((ext_vector_type(4)));
typedef short bf16x8 __attribute__((ext_vector_type(8)));
typedef unsigned short u16x8 __attribute__((ext_vector_type(8)));

#define AS1 __attribute__((address_space(1)))
#define AS3 __attribute__((address_space(3)))

__device__ __forceinline__ unsigned short f2bf(float f) {
  union { float f; uint32_t u; } v; v.f = f;
  uint32_t u = v.u;
  uint32_t r = (u + 0x7FFFu + ((u >> 16) & 1u)) >> 16;
  return (unsigned short)r;
}
__device__ __forceinline__ float bf2f(unsigned short s) {
  union { uint32_t u; float f; } v; v.u = ((uint32_t)s) << 16;
  return v.f;
}

// ---------------- prep: adj f32->bf16 + rowsum (blocks 0..4095, 1 row each)
// ----------------       x transpose -> Xt[s*32+f][j] bf16 (blocks 4096..8191)
__global__ __launch_bounds__(256) void k_prep(const float* __restrict__ adj,
                                              unsigned short* __restrict__ adjb,
                                              float* __restrict__ rowsum,
                                              const float* __restrict__ x,
                                              unsigned short* __restrict__ Xt) {
  __shared__ float xl[64][33];
  __shared__ float ps[4];
  int tid = threadIdx.x;
  if (blockIdx.x < 4096) {
    int row = blockIdx.x;
    const float4* src = (const float4*)(adj + (size_t)row * 4096);
    ushort4* dst = (ushort4*)(adjb + (size_t)row * 4096);
    float sum = 0.f;
    #pragma unroll
    for (int q = 0; q < 4; ++q) {
      int idx = q * 256 + tid;
      float4 v = src[idx];
      ushort4 r;
      r.x = f2bf(v.x); r.y = f2bf(v.y); r.z = f2bf(v.z); r.w = f2bf(v.w);
      dst[idx] = r;
      sum += (v.x + v.y) + (v.z + v.w);
    }
    #pragma unroll
    for (int off = 1; off < 64; off <<= 1) sum += __shfl_xor(sum, off);
    if ((tid & 63) == 0) ps[tid >> 6] = sum;
    __syncthreads();
    if (tid == 0) rowsum[row] = (ps[0] + ps[1]) + (ps[2] + ps[3]);
    return;
  }
  int bs = blockIdx.x - 4096;
  int s = bs >> 6, jb = (bs & 63) << 6;
  const float4* xg = (const float4*)(x + ((size_t)s * NN + jb) * FF);
  #pragma unroll
  for (int ii = 0; ii < 2; ++ii) {
    int idx = tid + ii * 256;
    float4 v = xg[idx];
    int j = idx >> 3, f = (idx & 7) << 2;
    xl[j][f] = v.x; xl[j][f + 1] = v.y; xl[j][f + 2] = v.z; xl[j][f + 3] = v.w;
  }
  __syncthreads();
  int f = tid >> 3, jc = tid & 7;
  u16x8 ov;
  #pragma unroll
  for (int jj = 0; jj < 8; ++jj) ov[jj] = (short)f2bf(xl[jc * 8 + jj][f]);
  *(u16x8*)(Xt + (size_t)(s * 32 + f) * 4096 + jb + jc * 8) = ov;
}

// =====================================================================
// GEMM-AX: C1[i][sf] = sum_j adj[i,j] * Xt[sf][j].  M=4096 N=2048 K=4096.
// 128x256 tile, BK=64, 8 waves (2x4), TRIPLE-buffered LDS (3x48KB):
// stage always targets tile t+2 (free by construction -> no WAR barrier).
// Per K-tile: 16 ds_read + 6 global_load_lds + 32 MFMA + vmcnt(6) + 1 barrier.
// =====================================================================
#define SBAR()   asm volatile("s_barrier" ::: "memory")
#define VMCNT6() asm volatile("s_waitcnt vmcnt(6)" ::: "memory")
#define VMCNT0() asm volatile("s_waitcnt vmcnt(0)" ::: "memory")

__global__ __launch_bounds__(512, 2) void k_gemmAX(
    const unsigned short* __restrict__ A,
    const unsigned short* __restrict__ B,
    unsigned short* __restrict__ C1) {
  __shared__ __align__(16) char lds[147456];
  const int tid = threadIdx.x;
  const int wid = tid >> 6, l = tid & 63;
  const int wr2 = wid >> 2, wc2 = wid & 3;

  int bid = blockIdx.x;
  int swz = (bid & 7) * 32 + (bid >> 3);   // bijective XCD swizzle (256 = 8*32)
  const int i0 = (swz >> 3) * 128;         // 32 i-tiles
  const int c0 = (swz & 7) * 256;          // 8 sf-tiles

  // fragment-read lane constants (chunk-XOR swizzle within 128B rows)
  const int aOffC = wr2 * 8192 + (l & 15) * 128;
  const int bOffC = 16384 + wc2 * 8192 + (l & 15) * 128;
  const int colKK0 = (((l >> 4) * 16)) ^ ((l & 7) << 4);
  const int colKK1 = ((64 + (l >> 4) * 16)) ^ ((l & 7) << 4);

  // staging: linear LDS dest (8KB region = 64 rows x 128B), inverse-swizzled source
  const int srow = tid >> 3;
  const int scol = (((tid & 7) ^ (srow & 7)) << 4);
  const char* gA = (const char*)A + (size_t)(i0 + srow) * 8192 + scol;
  const char* gB = (const char*)B + (size_t)(c0 + srow) * 8192 + scol;
  char* ldsW = (char*)lds + wid * 1024;
  const char* ldsR = (const char*)lds;

  f32x4 acc[4][4];
  #pragma unroll
  for (int m = 0; m < 4; ++m)
    #pragma unroll
    for (int n = 0; n < 4; ++n) acc[m][n] = {0.f, 0.f, 0.f, 0.f};

  bf16x8 af[4][2], bfr[2][2];

#define STAGE6(K2, BOFS) do {                                                        \
    __builtin_amdgcn_global_load_lds((const AS1 void*)(gA + (K2)),                   \
        (AS3 void*)(ldsW + (BOFS)), 16, 0, 0);                                       \
    __builtin_amdgcn_global_load_lds((const AS1 void*)(gA + 524288 + (K2)),          \
        (AS3 void*)(ldsW + (BOFS) + 8192), 16, 0, 0);                                \
    __builtin_amdgcn_global_load_lds((const AS1 void*)(gB + (K2)),                   \
        (AS3 void*)(ldsW + (BOFS) + 16384), 16, 0, 0);                               \
    __builtin_amdgcn_global_load_lds((const AS1 void*)(gB + 524288 + (K2)),          \
        (AS3 void*)(ldsW + (BOFS) + 24576), 16, 0, 0);                               \
    __builtin_amdgcn_global_load_lds((const AS1 void*)(gB + 1048576 + (K2)),         \
        (AS3 void*)(ldsW + (BOFS) + 32768), 16, 0, 0);                               \
    __builtin_amdgcn_global_load_lds((const AS1 void*)(gB + 1572864 + (K2)),         \
        (AS3 void*)(ldsW + (BOFS) + 40960), 16, 0, 0);                               \
  } while (0)

#define READ_AF(BOFS) do {                                                           \
    _Pragma("unroll")                                                                \
    for (int _m = 0; _m < 4; ++_m) {                                                 \
      const char* _p = ldsR + (BOFS) + aOffC + _m * 2048;                            \
      af[_m][0] = *(const bf16x8*)(_p + colKK0);                                     \
      af[_m][1] = *(const bf16x8*)(_p + colKK1);                                     \
    } } while (0)

#define READ_B(BOFS, NH) do {                                                        \
    _Pragma("unroll")                                                                \
    for (int _j = 0; _j < 2; ++_j) {                                                 \
      const char* _p = ldsR + (BOFS) + bOffC + ((NH) * 2 + _j) * 2048;               \
      bfr[_j][0] = *(const bf16x8*)(_p + colKK0);                                    \
      bfr[_j][1] = *(const bf16x8*)(_p + colKK1);                                    \
    } } while (0)

#define MFMA_H(NH) do {                                                              \
    __builtin_amdgcn_s_setprio(1);                                                   \
    _Pragma("unroll")                                                                \
    for (int _kk = 0; _kk < 2; ++_kk)                                                \
      _Pragma("unroll")                                                              \
      for (int _m = 0; _m < 4; ++_m)                                                 \
        _Pragma("unroll")                                                            \
        for (int _j = 0; _j < 2; ++_j)                                               \
          acc[_m][(NH) * 2 + _j] = __builtin_amdgcn_mfma_f32_16x16x32_bf16(          \
              af[_m][_kk], bfr[_j][_kk], acc[_m][(NH) * 2 + _j], 0, 0, 0);           \
    __builtin_amdgcn_s_setprio(0);                                                   \
  } while (0)

  // Prologue: tile0 -> buf0, tile1 -> buf1 (12 ops); vmcnt(6) completes tile0.
  STAGE6(0, 0);
  STAGE6(128, 49152);
  VMCNT6();
  SBAR();

  int bofs = 0, bofs2 = 98304;
  for (int kt = 0; kt < 64; ++kt) {
    const int k2 = ((kt + 2) & 63) * 128;
    READ_AF(bofs);
    READ_B(bofs, 0);
    STAGE6(k2, bofs2);        // tile kt+2 -> buf (kt+2)%3; never aliases live data
    MFMA_H(0);
    READ_B(bofs, 1);
    MFMA_H(1);
    VMCNT6();                 // certifies tile kt+1 (own 6 ops); barrier globalizes
    SBAR();
    bofs = (bofs == 98304) ? 0 : bofs + 49152;
    bofs2 = (bofs2 == 98304) ? 0 : bofs2 + 49152;
  }
  VMCNT0();

  // Epilogue: store C1 bf16 (no activation here).
  const int rb = i0 + wr2 * 64 + (l >> 4) * 4;
  const int cb = c0 + wc2 * 64 + (l & 15);
  #pragma unroll
  for (int m = 0; m < 4; ++m)
    #pragma unroll
    for (int r = 0; r < 4; ++r) {
      const size_t ro = (size_t)(rb + m * 16 + r) * 2048;
      #pragma unroll
      for (int n = 0; n < 4; ++n)
        C1[ro + cb + n * 16] = f2bf(acc[m][n][r]);
    }
}

// ---------------- gcn1out: h = relu(C1@W1 + rowsum*b1); B2t = h@W2 + b2 ----------------
__global__ __launch_bounds__(256) void k_gcn1out(
    const unsigned short* __restrict__ C1, const float* __restrict__ rowsum,
    const float* __restrict__ W1, const float* __restrict__ b1,
    const float* __restrict__ W2, const float* __restrict__ b2,
    unsigned short* __restrict__ B2t) {
  __shared__ float w1l[2048];
  __shared__ float b1l[64];
  __shared__ float w2l[128];
  __shared__ float b2l[2];
  int tid = threadIdx.x;
  #pragma unroll
  for (int q = 0; q < 8; ++q) w1l[q * 256 + tid] = W1[q * 256 + tid];
  if (tid < 64) b1l[tid] = b1[tid];
  if (tid < 128) w2l[tid] = W2[tid];
  if (tid < 2) b2l[tid] = b2[tid];
  __syncthreads();
  int s = blockIdx.x & 63, ib = blockIdx.x >> 6;
  int i = ib * 256 + tid;
  const u16x8* cp = (const u16x8*)(C1 + (size_t)i * 2048 + s * 32);
  float cf[32];
  #pragma unroll
  for (int q = 0; q < 4; ++q) {
    u16x8 v = cp[q];
    #pragma unroll
    for (int e = 0; e < 8; ++e) cf[q * 8 + e] = bf2f((unsigned short)v[e]);
  }
  float rs = rowsum[i];
  const f32x4* b1v = (const f32x4*)b1l;
  f32x4 h[16];
  #pragma unroll
  for (int t = 0; t < 16; ++t) h[t] = rs * b1v[t];
  #pragma unroll
  for (int f = 0; f < 32; ++f) {
    float c = cf[f];
    const f32x4* wrow = (const f32x4*)(w1l + f * 64);
    #pragma unroll
    for (int t = 0; t < 16; ++t) h[t] += c * wrow[t];   // wave-uniform b128 broadcast
  }
  float o0 = b2l[0], o1 = b2l[1];
  #pragma unroll
  for (int t = 0; t < 16; ++t)
    #pragma unroll
    for (int e = 0; e < 4; ++e) {
      float a = h[t][e];
      a = a > 0.f ? a : 0.f;
      o0 += a * w2l[(t * 4 + e) * 2];
      o1 += a * w2l[(t * 4 + e) * 2 + 1];
    }
  B2t[(size_t)(s * 2 + 0) * 4096 + i] = f2bf(o0);
  B2t[(size_t)(s * 2 + 1) * 4096 + i] = f2bf(o1);
}

// ---------------- shared MFMA GEMM core (m97-style, used by gemm2) ----------------
__device__ __forceinline__ void gemm_core(const unsigned short* __restrict__ A,
                                          const unsigned short* __restrict__ B,
                                          int i0, int c0, int k0base, int ksteps,
                                          f32x4 acc[4][4],
                                          unsigned short* Als, unsigned short* Bls) {
  const int tid = threadIdx.x;
  const int w = tid >> 6, l = tid & 63;
  const int srow = (l >> 2);
  const int scol = (l & 3) * 16;   // bytes within 64B row
  for (int kt = 0; kt < ksteps; ++kt) {
    int k0 = k0base + kt * 32;
    #pragma unroll
    for (int q = 0; q < 2; ++q) {
      int r = w * 32 + q * 16 + srow;
      const char* ga = (const char*)(A + (size_t)(i0 + r) * 4096 + k0) + scol;
      __builtin_amdgcn_global_load_lds(
          (const AS1 void*)ga,
          (AS3 void*)((char*)Als + w * 2048 + q * 1024), 16, 0, 0);
      const char* gb = (const char*)(B + (size_t)(c0 + r) * 4096 + k0) + scol;
      __builtin_amdgcn_global_load_lds(
          (const AS1 void*)gb,
          (AS3 void*)((char*)Bls + w * 2048 + q * 1024), 16, 0, 0);
    }
    __syncthreads();
    const int wr = w >> 1, wc = w & 1;
    bf16x8 af[4], bff[4];
    #pragma unroll
    for (int m = 0; m < 4; ++m)
      af[m] = *(const bf16x8*)(Als + (wr * 64 + m * 16 + (l & 15)) * 32 + (l >> 4) * 8);
    #pragma unroll
    for (int n = 0; n < 4; ++n)
      bff[n] = *(const bf16x8*)(Bls + (wc * 64 + n * 16 + (l & 15)) * 32 + (l >> 4) * 8);
    #pragma unroll
    for (int m = 0; m < 4; ++m)
      #pragma unroll
      for (int n = 0; n < 4; ++n)
        acc[m][n] = __builtin_amdgcn_mfma_f32_16x16x32_bf16(af[m], bff[n], acc[m][n], 0, 0, 0);
    __syncthreads();
  }
}

// ---------------- GEMM2 split-K: Gp[ks][i][c2] partial f32 ----------------
__global__ __launch_bounds__(256) void k_gemm2(const unsigned short* __restrict__ A,
                                               const unsigned short* __restrict__ B,
                                               float* __restrict__ Gp) {
  __shared__ unsigned short Als[128 * 32], Bls[128 * 32];
  int id = blockIdx.x;
  int bi = id & 31, ks = id >> 5;
  int i0 = bi * 128;
  f32x4 acc[4][4];
  #pragma unroll
  for (int m = 0; m < 4; ++m)
    #pragma unroll
    for (int n = 0; n < 4; ++n) acc[m][n] = {0.f, 0.f, 0.f, 0.f};
  gemm_core(A, B, i0, 0, ks * 512, 16, acc, Als, Bls);
  float* outp = Gp + (size_t)ks * 4096 * 128;
  int l = threadIdx.x & 63, w = threadIdx.x >> 6;
  int wr = w >> 1, wc = w & 1;
  int rbase = i0 + wr * 64 + (l >> 4) * 4;
  int cbase = wc * 64 + (l & 15);
  #pragma unroll
  for (int m = 0; m < 4; ++m)
    #pragma unroll
    for (int n = 0; n < 4; ++n)
      #pragma unroll
      for (int r = 0; r < 4; ++r)
        outp[(size_t)(rbase + m * 16 + r) * 128 + cbase + n * 16] = acc[m][n][r];
}

// ---------------- reduce split-K + log_softmax -> R[s][i*2+o] f32 ----------------
__global__ __launch_bounds__(256) void k_lsm(const float* __restrict__ Gp,
                                             float* __restrict__ Rm) {
  __shared__ float Gacc[32][130];
  int i0 = blockIdx.x * 32;
  int tid = threadIdx.x;
  float4 v[4];
  #pragma unroll
  for (int i = 0; i < 4; ++i) v[i] = {0.f, 0.f, 0.f, 0.f};
  for (int ks = 0; ks < 8; ++ks) {
    const float4* gp4 = ((const float4*)Gp) + (size_t)ks * 131072 + (size_t)i0 * 32;
    #pragma unroll
    for (int i = 0; i < 4; ++i) {
      float4 t = gp4[tid + i * 256];
      v[i].x += t.x; v[i].y += t.y; v[i].z += t.z; v[i].w += t.w;
    }
  }
  #pragma unroll
  for (int i = 0; i < 4; ++i) {
    int f4i = tid + i * 256, row = f4i >> 5, c = (f4i & 31) * 4;
    Gacc[row][c] = v[i].x; Gacc[row][c + 1] = v[i].y;
    Gacc[row][c + 2] = v[i].z; Gacc[row][c + 3] = v[i].w;
  }
  __syncthreads();
  #pragma unroll
  for (int j = 0; j < 8; ++j) {
    int p = j * 256 + tid;
    int ii = p & 31, s = p >> 5;
    float g0 = Gacc[ii][s * 2], g1 = Gacc[ii][s * 2 + 1];
    float m = fmaxf(g0, g1);
    float lse = m + logf(expf(g0 - m) + expf(g1 - m));
    float2 o_; o_.x = g0 - lse; o_.y = g1 - lse;
    *((float2*)(Rm + (size_t)s * 8192 + (size_t)(i0 + ii) * 2)) = o_;
  }
}

// ---------------- gi0 partial: part[ks][t][g] = R[t] . Wih0[g] over c-range ----------------
__global__ __launch_bounds__(256) void k_gi0(const float* __restrict__ Rm,
                                             const float* __restrict__ Wih0,
                                             float* __restrict__ part) {
  __shared__ float4 Wl[4 * 128];
  int gb = blockIdx.x % 48, ks = blockIdx.x / 48;
  int c0 = ks * 512;
  int tid = threadIdx.x;
  #pragma unroll
  for (int i = 0; i < 2; ++i) {
    int idx = tid + i * 256;
    int g = idx >> 7, c4 = idx & 127;
    Wl[g * 128 + c4] = ((const float4*)(Wih0 + (size_t)(gb * 4 + g) * 8192 + c0))[c4];
  }
  __syncthreads();
  int w = tid >> 6, lane = tid & 63;
  for (int pass = 0; pass < 16; ++pass) {
    int t = pass * 4 + w;
    float a0 = 0.f, a1 = 0.f, a2 = 0.f, a3 = 0.f;
    const float4* rg = (const float4*)(Rm + (size_t)t * 8192 + c0);
    #pragma unroll
    for (int i = 0; i < 2; ++i) {
      int c4 = i * 64 + lane;
      float4 r4 = rg[c4];
      float4 w0 = Wl[c4], w1 = Wl[128 + c4], w2 = Wl[256 + c4], w3 = Wl[384 + c4];
      a0 += r4.x * w0.x + r4.y * w0.y + r4.z * w0.z + r4.w * w0.w;
      a1 += r4.x * w1.x + r4.y * w1.y + r4.z * w1.z + r4.w * w1.w;
      a2 += r4.x * w2.x + r4.y * w2.y + r4.z * w2.z + r4.w * w2.w;
      a3 += r4.x * w3.x + r4.y * w3.y + r4.z * w3.z + r4.w * w3.w;
    }
    #pragma unroll
    for (int off = 1; off < 64; off <<= 1) {
      a0 += __shfl_xor(a0, off);
      a1 += __shfl_xor(a1, off);
      a2 += __shfl_xor(a2, off);
      a3 += __shfl_xor(a3, off);
    }
    if (lane == 0) {
      float4 o_; o_.x = a0; o_.y = a1; o_.z = a2; o_.w = a3;
      *((float4*)(part + ((size_t)ks * 64 + t) * 192 + gb * 4)) = o_;
    }
  }
}

__global__ __launch_bounds__(256) void k_gi0red(const float* __restrict__ part,
                                                const float* __restrict__ bih0,
                                                float* __restrict__ gi0) {
  int idx = blockIdx.x * 256 + threadIdx.x;
  if (idx < 12288) {
    float s_ = bih0[idx % 192];
    for (int ks = 0; ks < 16; ++ks) s_ += part[ks * 12288 + idx];
    gi0[idx] = s_;
  }
}

// ---------------- fused 2-layer GRU, batch 1, weights in VGPRs ----------------
__global__ __launch_bounds__(192) void k_gru(const float* __restrict__ gi0,
                                             const float* __restrict__ Whh0,
                                             const float* __restrict__ bhh0,
                                             const float* __restrict__ Wih1,
                                             const float* __restrict__ Whh1,
                                             const float* __restrict__ bih1,
                                             const float* __restrict__ bhh1,
                                             float* __restrict__ out) {
  __shared__ float gil[64][192];
  __shared__ float h0s[64], h1s[64], ys0s[64], gA[192], uA[192], vA[192];
  int g = threadIdx.x;
  float w0[64], wi1[64], wh1[64];
  #pragma unroll
  for (int k = 0; k < 16; ++k) {
    float4 t0 = ((const float4*)(Whh0 + (size_t)g * 64))[k];
    float4 t1 = ((const float4*)(Wih1 + (size_t)g * 64))[k];
    float4 t2 = ((const float4*)(Whh1 + (size_t)g * 64))[k];
    w0[k * 4] = t0.x; w0[k * 4 + 1] = t0.y; w0[k * 4 + 2] = t0.z; w0[k * 4 + 3] = t0.w;
    wi1[k * 4] = t1.x; wi1[k * 4 + 1] = t1.y; wi1[k * 4 + 2] = t1.z; wi1[k * 4 + 3] = t1.w;
    wh1[k * 4] = t2.x; wh1[k * 4 + 1] = t2.y; wh1[k * 4 + 2] = t2.z; wh1[k * 4 + 3] = t2.w;
  }
  float bh0 = bhh0[g], bi1 = bih1[g], bh1 = bhh1[g];
  {
    float4* gf = (float4*)&gil[0][0];
    const float4* gs = (const float4*)gi0;
    #pragma unroll
    for (int i = 0; i < 16; ++i) gf[i * 192 + g] = gs[i * 192 + g];
  }
  if (g < 64) { h0s[g] = 0.f; h1s[g] = 0.f; ys0s[g] = 0.f; }
  __syncthreads();

  for (int t = 0; t <= 64; ++t) {
    const int tt = t & 63;
    float a0 = 0.f, a1 = 0.f, a2 = 0.f, a3 = 0.f;
    float b0 = 0.f, b1_ = 0.f, b2_ = 0.f, b3 = 0.f;
    float c0 = 0.f, c1 = 0.f, c2 = 0.f, c3 = 0.f;
    #pragma unroll
    for (int k = 0; k < 16; ++k) {
      float4 h4 = *(const float4*)&h0s[k * 4];
      float4 y4 = *(const float4*)&ys0s[k * 4];
      float4 g4 = *(const float4*)&h1s[k * 4];
      a0 += w0[k * 4] * h4.x;  a1 += w0[k * 4 + 1] * h4.y;
      a2 += w0[k * 4 + 2] * h4.z;  a3 += w0[k * 4 + 3] * h4.w;
      b0 += wi1[k * 4] * y4.x; b1_ += wi1[k * 4 + 1] * y4.y;
      b2_ += wi1[k * 4 + 2] * y4.z; b3 += wi1[k * 4 + 3] * y4.w;
      c0 += wh1[k * 4] * g4.x; c1 += wh1[k * 4 + 1] * g4.y;
      c2 += wh1[k * 4 + 2] * g4.z; c3 += wh1[k * 4 + 3] * g4.w;
    }
    float gh = (a0 + a1) + (a2 + a3) + bh0;
    gA[g] = (g < 128) ? (gil[tt][g] + gh) : gh;
    uA[g] = (b0 + b1_) + (b2_ + b3) + bi1;
    vA[g] = (c0 + c1) + (c2 + c3) + bh1;
    __syncthreads();
    if (g < 64) {
      if (t < 64) {
        float r = 1.f / (1.f + expf(-gA[g]));
        float z = 1.f / (1.f + expf(-gA[g + 64]));
        float n = tanhf(gil[tt][128 + g] + r * gA[g + 128]);
        float hnew = (1.f - z) * n + z * h0s[g];
        h0s[g] = hnew; ys0s[g] = hnew;
      }
    } else if (g < 128 && t > 0) {
      int gg = g - 64;
      float r = 1.f / (1.f + expf(-(uA[gg] + vA[gg])));
      float z = 1.f / (1.f + expf(-(uA[gg + 64] + vA[gg + 64])));
      float n = tanhf(uA[gg + 128] + r * vA[gg + 128]);
      float h1new = (1.f - z) * n + z * h1s[gg];
      h1s[gg] = h1new;
      out[(t - 1) * 64 + gg] = h1new;
    }
    __syncthreads();
  }
  if (g < 64) { out[4096 + g] = h0s[g]; out[4096 + 64 + g] = h1s[g]; }
}

extern "C" void kernel_launch(void* const* d_in, const int* in_sizes, int n_in,
                              void* d_out, int out_size, void* d_ws, size_t ws_size,
                              hipStream_t stream) {
  const float* x    = (const float*)d_in[0];
  const float* adj  = (const float*)d_in[1];
  const float* W1   = (const float*)d_in[2];
  const float* b1   = (const float*)d_in[3];
  const float* W2   = (const float*)d_in[4];
  const float* b2   = (const float*)d_in[5];
  const float* Wih0 = (const float*)d_in[6];
  const float* Whh0 = (const float*)d_in[7];
  const float* bih0 = (const float*)d_in[8];
  const float* bhh0 = (const float*)d_in[9];
  const float* Wih1 = (const float*)d_in[10];
  const float* Whh1 = (const float*)d_in[11];
  const float* bih1 = (const float*)d_in[12];
  const float* bhh1 = (const float*)d_in[13];
  float* out = (float*)d_out;

  char* ws = (char*)d_ws;
  unsigned short* adjb = (unsigned short*)ws;                      // 33.55MB
  unsigned short* Xt   = (unsigned short*)(ws + 33554432);         // 16.78MB
  unsigned short* C1   = (unsigned short*)(ws + 50331648);         // 16.78MB
  float* rowsum        = (float*)(ws + 67108864);                  // 16KB
  float* Gp            = (float*)(ws + 67125248);                  // 16.78MB
  float* Rm            = (float*)(ws + 83902464);                  // 2MB
  float* part          = (float*)(ws + 85999616);                  // 768KB
  float* gi0           = (float*)(ws + 86786048);                  // 48KB
  unsigned short* B2t  = (unsigned short*)(ws + 86835200);         // 1MB

  k_prep<<<8192, 256, 0, stream>>>(adj, adjb, rowsum, x, Xt);
  k_gemmAX<<<256, 512, 0, stream>>>(adjb, Xt, C1);
  k_gcn1out<<<1024, 256, 0, stream>>>(C1, rowsum, W1, b1, W2, b2, B2t);
  k_gemm2<<<256, 256, 0, stream>>>(adjb, B2t, Gp);
  k_lsm<<<128, 256, 0, stream>>>(Gp, Rm);
  k_gi0<<<768, 256, 0, stream>>>(Rm, Wih0, part);
  k_gi0red<<<48, 256, 0, stream>>>(part, bih0, gi0);
  k_gru<<<1, 192, 0, stream>>>(gi0, Whh0, bhh0, Wih1, Whh1, bih1, bhh1, out);
}

// Round 6
// 186.649 us; speedup vs baseline: 1.8281x; 1.4123x over previous
//
#include <hip/hip_runtime.h>
#include <stdint.h>

#define SS 64
#define NN 4096
#define FF 32
#define HH 64
#define OO 2
#define G3 192

typedef float f32x4 __attribute__((ext_vector_type(4)));
typedef short bf16x8 __attribute__((ext_vector_type(8)));
typedef unsigned short u16x8 __attribute__((ext_vector_type(8)));

#define AS1 __attribute__((address_space(1)))
#define AS3 __attribute__((address_space(3)))

__device__ __forceinline__ unsigned short f2bf(float f) {
  union { float f; uint32_t u; } v; v.f = f;
  uint32_t u = v.u;
  uint32_t r = (u + 0x7FFFu + ((u >> 16) & 1u)) >> 16;
  return (unsigned short)r;
}
__device__ __forceinline__ float bf2f(unsigned short s) {
  union { uint32_t u; float f; } v; v.u = ((uint32_t)s) << 16;
  return v.f;
}

// ---------------- prep: adj f32->bf16 + rowsum (blocks 0..4095, 1 row each)
// ----------------       x transpose -> Xt[s*32+f][j] bf16 (blocks 4096..8191)
__global__ __launch_bounds__(256) void k_prep(const float* __restrict__ adj,
                                              unsigned short* __restrict__ adjb,
                                              float* __restrict__ rowsum,
                                              const float* __restrict__ x,
                                              unsigned short* __restrict__ Xt) {
  __shared__ float xl[64][33];
  __shared__ float ps[4];
  int tid = threadIdx.x;
  if (blockIdx.x < 4096) {
    int row = blockIdx.x;
    const float4* src = (const float4*)(adj + (size_t)row * 4096);
    ushort4* dst = (ushort4*)(adjb + (size_t)row * 4096);
    float sum = 0.f;
    #pragma unroll
    for (int q = 0; q < 4; ++q) {
      int idx = q * 256 + tid;
      float4 v = src[idx];
      ushort4 r;
      r.x = f2bf(v.x); r.y = f2bf(v.y); r.z = f2bf(v.z); r.w = f2bf(v.w);
      dst[idx] = r;
      sum += (v.x + v.y) + (v.z + v.w);
    }
    #pragma unroll
    for (int off = 1; off < 64; off <<= 1) sum += __shfl_xor(sum, off);
    if ((tid & 63) == 0) ps[tid >> 6] = sum;
    __syncthreads();
    if (tid == 0) rowsum[row] = (ps[0] + ps[1]) + (ps[2] + ps[3]);
    return;
  }
  int bs = blockIdx.x - 4096;
  int s = bs >> 6, jb = (bs & 63) << 6;
  const float4* xg = (const float4*)(x + ((size_t)s * NN + jb) * FF);
  #pragma unroll
  for (int ii = 0; ii < 2; ++ii) {
    int idx = tid + ii * 256;
    float4 v = xg[idx];
    int j = idx >> 3, f = (idx & 7) << 2;
    xl[j][f] = v.x; xl[j][f + 1] = v.y; xl[j][f + 2] = v.z; xl[j][f + 3] = v.w;
  }
  __syncthreads();
  int f = tid >> 3, jc = tid & 7;
  u16x8 ov;
  #pragma unroll
  for (int jj = 0; jj < 8; ++jj) ov[jj] = (short)f2bf(xl[jc * 8 + jj][f]);
  *(u16x8*)(Xt + (size_t)(s * 32 + f) * 4096 + jb + jc * 8) = ov;
}

// =====================================================================
// GEMM-AX: C1[i][sf] = sum_j adj[i,j] * Xt[sf][j].  M=4096 N=2048 K=4096.
// 128x256 tile, BK=64, 8 waves (2x4), TRIPLE-buffered LDS (3x48KB).
// =====================================================================
#define SBAR()   asm volatile("s_barrier" ::: "memory")
#define VMCNT6() asm volatile("s_waitcnt vmcnt(6)" ::: "memory")
#define VMCNT0() asm volatile("s_waitcnt vmcnt(0)" ::: "memory")
#define LBAR()   asm volatile("s_waitcnt lgkmcnt(0)\n\ts_barrier" ::: "memory")

__global__ __launch_bounds__(512, 2) void k_gemmAX(
    const unsigned short* __restrict__ A,
    const unsigned short* __restrict__ B,
    unsigned short* __restrict__ C1) {
  __shared__ __align__(16) char lds[147456];
  const int tid = threadIdx.x;
  const int wid = tid >> 6, l = tid & 63;
  const int wr2 = wid >> 2, wc2 = wid & 3;

  int bid = blockIdx.x;
  int swz = (bid & 7) * 32 + (bid >> 3);   // bijective XCD swizzle (256 = 8*32)
  const int i0 = (swz >> 3) * 128;         // 32 i-tiles
  const int c0 = (swz & 7) * 256;          // 8 sf-tiles

  const int aOffC = wr2 * 8192 + (l & 15) * 128;
  const int bOffC = 16384 + wc2 * 8192 + (l & 15) * 128;
  const int colKK0 = (((l >> 4) * 16)) ^ ((l & 7) << 4);
  const int colKK1 = ((64 + (l >> 4) * 16)) ^ ((l & 7) << 4);

  const int srow = tid >> 3;
  const int scol = (((tid & 7) ^ (srow & 7)) << 4);
  const char* gA = (const char*)A + (size_t)(i0 + srow) * 8192 + scol;
  const char* gB = (const char*)B + (size_t)(c0 + srow) * 8192 + scol;
  char* ldsW = (char*)lds + wid * 1024;
  const char* ldsR = (const char*)lds;

  f32x4 acc[4][4];
  #pragma unroll
  for (int m = 0; m < 4; ++m)
    #pragma unroll
    for (int n = 0; n < 4; ++n) acc[m][n] = {0.f, 0.f, 0.f, 0.f};

  bf16x8 af[4][2], bfr[2][2];

#define STAGE6(K2, BOFS) do {                                                        \
    __builtin_amdgcn_global_load_lds((const AS1 void*)(gA + (K2)),                   \
        (AS3 void*)(ldsW + (BOFS)), 16, 0, 0);                                       \
    __builtin_amdgcn_global_load_lds((const AS1 void*)(gA + 524288 + (K2)),          \
        (AS3 void*)(ldsW + (BOFS) + 8192), 16, 0, 0);                                \
    __builtin_amdgcn_global_load_lds((const AS1 void*)(gB + (K2)),                   \
        (AS3 void*)(ldsW + (BOFS) + 16384), 16, 0, 0);                               \
    __builtin_amdgcn_global_load_lds((const AS1 void*)(gB + 524288 + (K2)),          \
        (AS3 void*)(ldsW + (BOFS) + 24576), 16, 0, 0);                               \
    __builtin_amdgcn_global_load_lds((const AS1 void*)(gB + 1048576 + (K2)),         \
        (AS3 void*)(ldsW + (BOFS) + 32768), 16, 0, 0);                               \
    __builtin_amdgcn_global_load_lds((const AS1 void*)(gB + 1572864 + (K2)),         \
        (AS3 void*)(ldsW + (BOFS) + 40960), 16, 0, 0);                               \
  } while (0)

#define READ_AF(BOFS) do {                                                           \
    _Pragma("unroll")                                                                \
    for (int _m = 0; _m < 4; ++_m) {                                                 \
      const char* _p = ldsR + (BOFS) + aOffC + _m * 2048;                            \
      af[_m][0] = *(const bf16x8*)(_p + colKK0);                                     \
      af[_m][1] = *(const bf16x8*)(_p + colKK1);                                     \
    } } while (0)

#define READ_B(BOFS, NH) do {                                                        \
    _Pragma("unroll")                                                                \
    for (int _j = 0; _j < 2; ++_j) {                                                 \
      const char* _p = ldsR + (BOFS) + bOffC + ((NH) * 2 + _j) * 2048;               \
      bfr[_j][0] = *(const bf16x8*)(_p + colKK0);                                    \
      bfr[_j][1] = *(const bf16x8*)(_p + colKK1);                                    \
    } } while (0)

#define MFMA_H(NH) do {                                                              \
    __builtin_amdgcn_s_setprio(1);                                                   \
    _Pragma("unroll")                                                                \
    for (int _kk = 0; _kk < 2; ++_kk)                                                \
      _Pragma("unroll")                                                              \
      for (int _m = 0; _m < 4; ++_m)                                                 \
        _Pragma("unroll")                                                            \
        for (int _j = 0; _j < 2; ++_j)                                               \
          acc[_m][(NH) * 2 + _j] = __builtin_amdgcn_mfma_f32_16x16x32_bf16(          \
              af[_m][_kk], bfr[_j][_kk], acc[_m][(NH) * 2 + _j], 0, 0, 0);           \
    __builtin_amdgcn_s_setprio(0);                                                   \
  } while (0)

  STAGE6(0, 0);
  STAGE6(128, 49152);
  VMCNT6();
  SBAR();

  int bofs = 0, bofs2 = 98304;
  for (int kt = 0; kt < 64; ++kt) {
    const int k2 = ((kt + 2) & 63) * 128;
    READ_AF(bofs);
    READ_B(bofs, 0);
    STAGE6(k2, bofs2);
    MFMA_H(0);
    READ_B(bofs, 1);
    MFMA_H(1);
    VMCNT6();
    SBAR();
    bofs = (bofs == 98304) ? 0 : bofs + 49152;
    bofs2 = (bofs2 == 98304) ? 0 : bofs2 + 49152;
  }
  VMCNT0();

  const int rb = i0 + wr2 * 64 + (l >> 4) * 4;
  const int cb = c0 + wc2 * 64 + (l & 15);
  #pragma unroll
  for (int m = 0; m < 4; ++m)
    #pragma unroll
    for (int r = 0; r < 4; ++r) {
      const size_t ro = (size_t)(rb + m * 16 + r) * 2048;
      #pragma unroll
      for (int n = 0; n < 4; ++n)
        C1[ro + cb + n * 16] = f2bf(acc[m][n][r]);
    }
}

// ---------------- gcn1out: h = relu(C1@W1 + rowsum*b1); B2t = h@W2 + b2 ----------------
__global__ __launch_bounds__(256) void k_gcn1out(
    const unsigned short* __restrict__ C1, const float* __restrict__ rowsum,
    const float* __restrict__ W1, const float* __restrict__ b1,
    const float* __restrict__ W2, const float* __restrict__ b2,
    unsigned short* __restrict__ B2t) {
  __shared__ float w1l[2048];
  __shared__ float b1l[64];
  __shared__ float w2l[128];
  __shared__ float b2l[2];
  int tid = threadIdx.x;
  #pragma unroll
  for (int q = 0; q < 8; ++q) w1l[q * 256 + tid] = W1[q * 256 + tid];
  if (tid < 64) b1l[tid] = b1[tid];
  if (tid < 128) w2l[tid] = W2[tid];
  if (tid < 2) b2l[tid] = b2[tid];
  __syncthreads();
  int s = blockIdx.x & 63, ib = blockIdx.x >> 6;
  int i = ib * 256 + tid;
  const u16x8* cp = (const u16x8*)(C1 + (size_t)i * 2048 + s * 32);
  float cf[32];
  #pragma unroll
  for (int q = 0; q < 4; ++q) {
    u16x8 v = cp[q];
    #pragma unroll
    for (int e = 0; e < 8; ++e) cf[q * 8 + e] = bf2f((unsigned short)v[e]);
  }
  float rs = rowsum[i];
  const f32x4* b1v = (const f32x4*)b1l;
  f32x4 h[16];
  #pragma unroll
  for (int t = 0; t < 16; ++t) h[t] = rs * b1v[t];
  #pragma unroll
  for (int f = 0; f < 32; ++f) {
    float c = cf[f];
    const f32x4* wrow = (const f32x4*)(w1l + f * 64);
    #pragma unroll
    for (int t = 0; t < 16; ++t) h[t] += c * wrow[t];
  }
  float o0 = b2l[0], o1 = b2l[1];
  #pragma unroll
  for (int t = 0; t < 16; ++t)
    #pragma unroll
    for (int e = 0; e < 4; ++e) {
      float a = h[t][e];
      a = a > 0.f ? a : 0.f;
      o0 += a * w2l[(t * 4 + e) * 2];
      o1 += a * w2l[(t * 4 + e) * 2 + 1];
    }
  B2t[(size_t)(s * 2 + 0) * 4096 + i] = f2bf(o0);
  B2t[(size_t)(s * 2 + 1) * 4096 + i] = f2bf(o1);
}

// ---------------- shared MFMA GEMM core (m97-style, used by gemm2) ----------------
__device__ __forceinline__ void gemm_core(const unsigned short* __restrict__ A,
                                          const unsigned short* __restrict__ B,
                                          int i0, int c0, int k0base, int ksteps,
                                          f32x4 acc[4][4],
                                          unsigned short* Als, unsigned short* Bls) {
  const int tid = threadIdx.x;
  const int w = tid >> 6, l = tid & 63;
  const int srow = (l >> 2);
  const int scol = (l & 3) * 16;
  for (int kt = 0; kt < ksteps; ++kt) {
    int k0 = k0base + kt * 32;
    #pragma unroll
    for (int q = 0; q < 2; ++q) {
      int r = w * 32 + q * 16 + srow;
      const char* ga = (const char*)(A + (size_t)(i0 + r) * 4096 + k0) + scol;
      __builtin_amdgcn_global_load_lds(
          (const AS1 void*)ga,
          (AS3 void*)((char*)Als + w * 2048 + q * 1024), 16, 0, 0);
      const char* gb = (const char*)(B + (size_t)(c0 + r) * 4096 + k0) + scol;
      __builtin_amdgcn_global_load_lds(
          (const AS1 void*)gb,
          (AS3 void*)((char*)Bls + w * 2048 + q * 1024), 16, 0, 0);
    }
    __syncthreads();
    const int wr = w >> 1, wc = w & 1;
    bf16x8 af[4], bff[4];
    #pragma unroll
    for (int m = 0; m < 4; ++m)
      af[m] = *(const bf16x8*)(Als + (wr * 64 + m * 16 + (l & 15)) * 32 + (l >> 4) * 8);
    #pragma unroll
    for (int n = 0; n < 4; ++n)
      bff[n] = *(const bf16x8*)(Bls + (wc * 64 + n * 16 + (l & 15)) * 32 + (l >> 4) * 8);
    #pragma unroll
    for (int m = 0; m < 4; ++m)
      #pragma unroll
      for (int n = 0; n < 4; ++n)
        acc[m][n] = __builtin_amdgcn_mfma_f32_16x16x32_bf16(af[m], bff[n], acc[m][n], 0, 0, 0);
    __syncthreads();
  }
}

// ---------------- GEMM2 split-K: Gp[ks][i][c2] partial f32 ----------------
__global__ __launch_bounds__(256) void k_gemm2(const unsigned short* __restrict__ A,
                                               const unsigned short* __restrict__ B,
                                               float* __restrict__ Gp) {
  __shared__ unsigned short Als[128 * 32], Bls[128 * 32];
  int id = blockIdx.x;
  int bi = id & 31, ks = id >> 5;
  int i0 = bi * 128;
  f32x4 acc[4][4];
  #pragma unroll
  for (int m = 0; m < 4; ++m)
    #pragma unroll
    for (int n = 0; n < 4; ++n) acc[m][n] = {0.f, 0.f, 0.f, 0.f};
  gemm_core(A, B, i0, 0, ks * 512, 16, acc, Als, Bls);
  float* outp = Gp + (size_t)ks * 4096 * 128;
  int l = threadIdx.x & 63, w = threadIdx.x >> 6;
  int wr = w >> 1, wc = w & 1;
  int rbase = i0 + wr * 64 + (l >> 4) * 4;
  int cbase = wc * 64 + (l & 15);
  #pragma unroll
  for (int m = 0; m < 4; ++m)
    #pragma unroll
    for (int n = 0; n < 4; ++n)
      #pragma unroll
      for (int r = 0; r < 4; ++r)
        outp[(size_t)(rbase + m * 16 + r) * 128 + cbase + n * 16] = acc[m][n][r];
}

// ---------------- reduce split-K + log_softmax -> R[s][i*2+o] f32 ----------------
__global__ __launch_bounds__(256) void k_lsm(const float* __restrict__ Gp,
                                             float* __restrict__ Rm) {
  __shared__ float Gacc[32][130];
  int i0 = blockIdx.x * 32;
  int tid = threadIdx.x;
  float4 v[4];
  #pragma unroll
  for (int i = 0; i < 4; ++i) v[i] = {0.f, 0.f, 0.f, 0.f};
  for (int ks = 0; ks < 8; ++ks) {
    const float4* gp4 = ((const float4*)Gp) + (size_t)ks * 131072 + (size_t)i0 * 32;
    #pragma unroll
    for (int i = 0; i < 4; ++i) {
      float4 t = gp4[tid + i * 256];
      v[i].x += t.x; v[i].y += t.y; v[i].z += t.z; v[i].w += t.w;
    }
  }
  #pragma unroll
  for (int i = 0; i < 4; ++i) {
    int f4i = tid + i * 256, row = f4i >> 5, c = (f4i & 31) * 4;
    Gacc[row][c] = v[i].x; Gacc[row][c + 1] = v[i].y;
    Gacc[row][c + 2] = v[i].z; Gacc[row][c + 3] = v[i].w;
  }
  __syncthreads();
  #pragma unroll
  for (int j = 0; j < 8; ++j) {
    int p = j * 256 + tid;
    int ii = p & 31, s = p >> 5;
    float g0 = Gacc[ii][s * 2], g1 = Gacc[ii][s * 2 + 1];
    float m = fmaxf(g0, g1);
    float lse = m + logf(expf(g0 - m) + expf(g1 - m));
    float2 o_; o_.x = g0 - lse; o_.y = g1 - lse;
    *((float2*)(Rm + (size_t)s * 8192 + (size_t)(i0 + ii) * 2)) = o_;
  }
}

// ---------------- gi0 partial: part[ks][t][g] = R[t] . Wih0[g] over c-range ----------------
__global__ __launch_bounds__(256) void k_gi0(const float* __restrict__ Rm,
                                             const float* __restrict__ Wih0,
                                             float* __restrict__ part) {
  __shared__ float4 Wl[4 * 128];
  int gb = blockIdx.x % 48, ks = blockIdx.x / 48;
  int c0 = ks * 512;
  int tid = threadIdx.x;
  #pragma unroll
  for (int i = 0; i < 2; ++i) {
    int idx = tid + i * 256;
    int g = idx >> 7, c4 = idx & 127;
    Wl[g * 128 + c4] = ((const float4*)(Wih0 + (size_t)(gb * 4 + g) * 8192 + c0))[c4];
  }
  __syncthreads();
  int w = tid >> 6, lane = tid & 63;
  for (int pass = 0; pass < 16; ++pass) {
    int t = pass * 4 + w;
    float a0 = 0.f, a1 = 0.f, a2 = 0.f, a3 = 0.f;
    const float4* rg = (const float4*)(Rm + (size_t)t * 8192 + c0);
    #pragma unroll
    for (int i = 0; i < 2; ++i) {
      int c4 = i * 64 + lane;
      float4 r4 = rg[c4];
      float4 w0 = Wl[c4], w1 = Wl[128 + c4], w2 = Wl[256 + c4], w3 = Wl[384 + c4];
      a0 += r4.x * w0.x + r4.y * w0.y + r4.z * w0.z + r4.w * w0.w;
      a1 += r4.x * w1.x + r4.y * w1.y + r4.z * w1.z + r4.w * w1.w;
      a2 += r4.x * w2.x + r4.y * w2.y + r4.z * w2.z + r4.w * w2.w;
      a3 += r4.x * w3.x + r4.y * w3.y + r4.z * w3.z + r4.w * w3.w;
    }
    #pragma unroll
    for (int off = 1; off < 64; off <<= 1) {
      a0 += __shfl_xor(a0, off);
      a1 += __shfl_xor(a1, off);
      a2 += __shfl_xor(a2, off);
      a3 += __shfl_xor(a3, off);
    }
    if (lane == 0) {
      float4 o_; o_.x = a0; o_.y = a1; o_.z = a2; o_.w = a3;
      *((float4*)(part + ((size_t)ks * 64 + t) * 192 + gb * 4)) = o_;
    }
  }
}

__global__ __launch_bounds__(256) void k_gi0red(const float* __restrict__ part,
                                                const float* __restrict__ bih0,
                                                float* __restrict__ gi0) {
  int idx = blockIdx.x * 256 + threadIdx.x;
  if (idx < 12288) {
    float s_ = bih0[idx % 192];
    for (int ks = 0; ks < 16; ++ks) s_ += part[ks * 12288 + idx];
    gi0[idx] = s_;
  }
}

// =====================================================================
// MFMA GRU: 6 waves. Weights as A-frags in VGPRs (bf16). Per step:
// 2 broadcast ds_read_b128 (B-frags from bf16 h-vectors) + 12 MFMA +
// 6 predicated gate-writes, then 128 updater threads (f32 h in regs,
// fast exp2 transcendentals). Raw s_barrier with lgkm-only waits so
// the per-step out[] global store never blocks the chain.
// Matvecs: gout[0:192)=Whh0@h0, [192:384)=Wih1@h0 (ys0==h0 delayed),
// [384:576)=Whh1@h1.
// =====================================================================
__device__ __forceinline__ float fsigm(float x) {
  return __builtin_amdgcn_rcpf(1.f + __expf(-x));
}
__device__ __forceinline__ float ftanh(float x) {
  return 1.f - 2.f * __builtin_amdgcn_rcpf(1.f + __expf(2.f * x));
}

__global__ __launch_bounds__(384) void k_gru(const float* __restrict__ gi0,
                                             const float* __restrict__ Whh0,
                                             const float* __restrict__ bhh0,
                                             const float* __restrict__ Wih1,
                                             const float* __restrict__ Whh1,
                                             const float* __restrict__ bih1,
                                             const float* __restrict__ bhh1,
                                             float* __restrict__ out) {
  __shared__ float gil[64][192];                    // 48KB input gates (bih0 included)
  __shared__ float gout[576];
  __shared__ __align__(16) unsigned short hv[2][64]; // bf16 h0, h1
  const int tid = threadIdx.x;
  const int w = tid >> 6, l = tid & 63;
  const int matw = w >> 1, half = w & 1;
  const float* Wm = (matw == 0) ? Whh0 : (matw == 1 ? Wih1 : Whh1);
  const int mi = (matw == 2) ? 1 : 0;               // input vector: h0 or h1

  // A-fragments: 6 rowblocks x 2 k-halves, same assumed k-map as B (perm-invariant)
  bf16x8 afr[6][2];
  #pragma unroll
  for (int rbi = 0; rbi < 6; ++rbi) {
    int g = (half * 6 + rbi) * 16 + (l & 15);
    #pragma unroll
    for (int kh = 0; kh < 2; ++kh) {
      int k0 = kh * 32 + (l >> 4) * 8;
      const float4* src = (const float4*)(Wm + (size_t)g * 64 + k0);
      float4 v0 = src[0], v1 = src[1];
      bf16x8 a;
      a[0] = (short)f2bf(v0.x); a[1] = (short)f2bf(v0.y);
      a[2] = (short)f2bf(v0.z); a[3] = (short)f2bf(v0.w);
      a[4] = (short)f2bf(v1.x); a[5] = (short)f2bf(v1.y);
      a[6] = (short)f2bf(v1.z); a[7] = (short)f2bf(v1.w);
      afr[rbi][kh] = a;
    }
  }
  // preload gil (3072 float4 / 384 threads = 8 each)
  {
    float4* gf = (float4*)&gil[0][0];
    const float4* gs = (const float4*)gi0;
    #pragma unroll
    for (int i = 0; i < 8; ++i) gf[i * 384 + tid] = gs[i * 384 + tid];
  }
  if (tid < 128) hv[tid >> 6][tid & 63] = 0;

  // updater per-thread constants
  float hreg = 0.f;
  float bR = 0.f, bZ = 0.f, bNa = 0.f, bNb = 0.f;
  if (tid < 64) {
    bR = bhh0[tid]; bZ = bhh0[64 + tid]; bNa = bhh0[128 + tid];
  } else if (tid < 128) {
    int g = tid - 64;
    bR = bih1[g] + bhh1[g];
    bZ = bih1[64 + g] + bhh1[64 + g];
    bNa = bih1[128 + g];
    bNb = bhh1[128 + g];
  }
  LBAR();

  const int gwb = matw * 192 + half * 96 + (l >> 4) * 4;   // gout write base (rows)
  const f32x4 zacc = {0.f, 0.f, 0.f, 0.f};

  for (int i = 0; i <= 64; ++i) {
    // ---- matvec phase (all 6 waves) ----
    bf16x8 b0 = *(const bf16x8*)&hv[mi][(l >> 4) * 8];
    bf16x8 b1 = *(const bf16x8*)&hv[mi][32 + (l >> 4) * 8];
    #pragma unroll
    for (int rbi = 0; rbi < 6; ++rbi) {
      f32x4 a_ = __builtin_amdgcn_mfma_f32_16x16x32_bf16(afr[rbi][0], b0, zacc, 0, 0, 0);
      a_ = __builtin_amdgcn_mfma_f32_16x16x32_bf16(afr[rbi][1], b1, a_, 0, 0, 0);
      if (!(l & 15)) *(f32x4*)&gout[gwb + rbi * 16] = a_;
    }
    LBAR();
    // ---- update phase (threads 0..127) ----
    if (tid < 64) {
      if (i < 64) {
        float r = fsigm(gil[i][tid] + gout[tid] + bR);
        float z = fsigm(gil[i][64 + tid] + gout[64 + tid] + bZ);
        float n = ftanh(gil[i][128 + tid] + r * (gout[128 + tid] + bNa));
        hreg = (1.f - z) * n + z * hreg;
        hv[0][tid] = f2bf(hreg);
      }
    } else if (tid < 128 && i > 0) {
      int g = tid - 64;
      float r = fsigm(gout[192 + g] + gout[384 + g] + bR);
      float z = fsigm(gout[256 + g] + gout[448 + g] + bZ);
      float n = ftanh((gout[320 + g] + bNa) + r * (gout[512 + g] + bNb));
      hreg = (1.f - z) * n + z * hreg;
      hv[1][g] = f2bf(hreg);
      out[(i - 1) * 64 + g] = hreg;     // fire-and-forget (no vmcnt drain at barrier)
    }
    LBAR();
  }
  if (tid < 64) out[4096 + tid] = hreg;
  else if (tid < 128) out[4096 + 64 + (tid - 64)] = hreg;
}

extern "C" void kernel_launch(void* const* d_in, const int* in_sizes, int n_in,
                              void* d_out, int out_size, void* d_ws, size_t ws_size,
                              hipStream_t stream) {
  const float* x    = (const float*)d_in[0];
  const float* adj  = (const float*)d_in[1];
  const float* W1   = (const float*)d_in[2];
  const float* b1   = (const float*)d_in[3];
  const float* W2   = (const float*)d_in[4];
  const float* b2   = (const float*)d_in[5];
  const float* Wih0 = (const float*)d_in[6];
  const float* Whh0 = (const float*)d_in[7];
  const float* bih0 = (const float*)d_in[8];
  const float* bhh0 = (const float*)d_in[9];
  const float* Wih1 = (const float*)d_in[10];
  const float* Whh1 = (const float*)d_in[11];
  const float* bih1 = (const float*)d_in[12];
  const float* bhh1 = (const float*)d_in[13];
  float* out = (float*)d_out;

  char* ws = (char*)d_ws;
  unsigned short* adjb = (unsigned short*)ws;                      // 33.55MB
  unsigned short* Xt   = (unsigned short*)(ws + 33554432);         // 16.78MB
  unsigned short* C1   = (unsigned short*)(ws + 50331648);         // 16.78MB
  float* rowsum        = (float*)(ws + 67108864);                  // 16KB
  float* Gp            = (float*)(ws + 67125248);                  // 16.78MB
  float* Rm            = (float*)(ws + 83902464);                  // 2MB
  float* part          = (float*)(ws + 85999616);                  // 768KB
  float* gi0           = (float*)(ws + 86786048);                  // 48KB
  unsigned short* B2t  = (unsigned short*)(ws + 86835200);         // 1MB

  k_prep<<<8192, 256, 0, stream>>>(adj, adjb, rowsum, x, Xt);
  k_gemmAX<<<256, 512, 0, stream>>>(adjb, Xt, C1);
  k_gcn1out<<<1024, 256, 0, stream>>>(C1, rowsum, W1, b1, W2, b2, B2t);
  k_gemm2<<<256, 256, 0, stream>>>(adjb, B2t, Gp);
  k_lsm<<<128, 256, 0, stream>>>(Gp, Rm);
  k_gi0<<<768, 256, 0, stream>>>(Rm, Wih0, part);
  k_gi0red<<<48, 256, 0, stream>>>(part, bih0, gi0);
  k_gru<<<1, 384, 0, stream>>>(gi0, Whh0, bhh0, Wih1, Whh1, bih1, bhh1, out);
}